// Round 10
// baseline (1638.801 us; speedup 1.0000x reference)
//
#include <hip/hip_runtime.h>
#include <hip/hip_bf16.h>
#include <stdint.h>

#define T_TOK 16384
#define D_DIM 1024
#define E_NUM 8
#define H_DIM 2752
#define NSLOT (T_TOK * 2)

typedef __bf16 bf16x8_t __attribute__((ext_vector_type(8)));
typedef float f32x4_t __attribute__((ext_vector_type(4)));

__device__ __forceinline__ uint16_t f2bf(float f) {
    union { float f; uint32_t u; } v; v.f = f;
    return (uint16_t)((v.u + 0x7FFFu + ((v.u >> 16) & 1u)) >> 16);  // RNE
}
__device__ __forceinline__ ushort4 f4_to_bf4(float4 v) {
    ushort4 r; r.x = f2bf(v.x); r.y = f2bf(v.y); r.z = f2bf(v.z); r.w = f2bf(v.w);
    return r;
}
// async global->LDS, 16B/lane; HW writes LDS at (wave-uniform base) + lane*16
__device__ __forceinline__ void gl_lds16(const uint16_t* g, uint16_t* l) {
    __builtin_amdgcn_global_load_lds((const __attribute__((address_space(1))) void*)g,
                                     (__attribute__((address_space(3))) void*)l,
                                     16, 0, 0);
}

// ---------------- router: fp64 logits, softmax top-2, NO atomics ------------
__global__ __launch_bounds__(256) void router_kernel(
    const float* __restrict__ x, const float* __restrict__ gw,
    int* __restrict__ topk_i, float* __restrict__ topk_w) {
    int tid = threadIdx.x;
    int t = blockIdx.x * 4 + (tid >> 6);
    int lane = tid & 63;
    const float* xr = x + (size_t)t * D_DIM;
    double acc[E_NUM];
#pragma unroll
    for (int e = 0; e < E_NUM; ++e) acc[e] = 0.0;
    for (int k = lane; k < D_DIM; k += 64) {
        double xv = (double)xr[k];
#pragma unroll
        for (int e = 0; e < E_NUM; ++e) acc[e] += xv * (double)gw[e * D_DIM + k];
    }
#pragma unroll
    for (int e = 0; e < E_NUM; ++e) {
        double v = acc[e];
        for (int off = 32; off > 0; off >>= 1) v += __shfl_down(v, off, 64);
        acc[e] = v;
    }
    if (lane == 0) {
        int i0 = 0; double m0 = acc[0];
#pragma unroll
        for (int e = 1; e < E_NUM; ++e) if (acc[e] > m0) { m0 = acc[e]; i0 = e; }
        int i1 = -1; double m1 = -1.0e300;
#pragma unroll
        for (int e = 0; e < E_NUM; ++e) if (e != i0 && acc[e] > m1) { m1 = acc[e]; i1 = e; }
        double e1 = exp(m1 - m0);
        double s = 1.0 + e1;
        topk_i[t * 2 + 0] = i0; topk_i[t * 2 + 1] = i1;
        topk_w[t * 2 + 0] = (float)(1.0 / s);
        topk_w[t * 2 + 1] = (float)(e1 / s);
    }
}

// ---------------- count: LDS-aggregated histogram (1024 global atomics) -----
__global__ __launch_bounds__(256) void count_kernel(
    const int* __restrict__ topk_i,
    int* __restrict__ counts_f, int* __restrict__ counts_s) {
    __shared__ int hf[E_NUM], hs[E_NUM];
    int tid = threadIdx.x;
    if (tid < E_NUM) { hf[tid] = 0; hs[tid] = 0; }
    __syncthreads();
    int t = blockIdx.x * 256 + tid;
    atomicAdd(&hf[topk_i[t * 2 + 0]], 1);
    atomicAdd(&hs[topk_i[t * 2 + 1]], 1);
    __syncthreads();
    if (tid < E_NUM) {
        if (hf[tid]) atomicAdd(&counts_f[tid], hf[tid]);
    } else if (tid < 2 * E_NUM) {
        int e = tid - E_NUM;
        if (hs[e]) atomicAdd(&counts_s[e], hs[e]);
    }
}

__global__ void prefix_kernel(const int* __restrict__ cf, const int* __restrict__ cs,
                              int* __restrict__ bases, int* __restrict__ splits,
                              int* __restrict__ cnts) {
    int s = 0;
    for (int e = 0; e < E_NUM; ++e) {
        bases[e] = s;
        splits[e] = s + cf[e];          // first-slot range: [base, split)
        cnts[e] = cf[e] + cs[e];        // second-slot range: [split, base+cnt)
        s += cnts[e];
    }
}

// ---------------- assign: block-aggregated ranks (1024 global atomics) ------
__global__ __launch_bounds__(256) void assign_kernel(
    const int* __restrict__ topk_i, const float* __restrict__ topk_w,
    const int* __restrict__ bases, const int* __restrict__ splits,
    int* __restrict__ fills_f, int* __restrict__ fills_s,
    int* __restrict__ slot_tok, float* __restrict__ slot_w) {
    __shared__ int hf[E_NUM], hs[E_NUM], bf[E_NUM], bs[E_NUM];
    int tid = threadIdx.x;
    if (tid < E_NUM) { hf[tid] = 0; hs[tid] = 0; }
    __syncthreads();
    int t = blockIdx.x * 256 + tid;
    int e0 = topk_i[t * 2 + 0], e1 = topk_i[t * 2 + 1];
    int r0 = atomicAdd(&hf[e0], 1);     // local rank within block, per expert
    int r1 = atomicAdd(&hs[e1], 1);
    __syncthreads();
    if (tid < E_NUM) {
        bf[tid] = hf[tid] ? atomicAdd(&fills_f[tid], hf[tid]) : 0;
    } else if (tid < 2 * E_NUM) {
        int e = tid - E_NUM;
        bs[e] = hs[e] ? atomicAdd(&fills_s[e], hs[e]) : 0;
    }
    __syncthreads();
    int s0 = bases[e0] + bf[e0] + r0;
    int s1 = splits[e1] + bs[e1] + r1;
    slot_tok[s0] = t; slot_w[s0] = topk_w[t * 2 + 0];
    slot_tok[s1] = t; slot_w[s1] = topk_w[t * 2 + 1];
}

// ---------------- converts --------------------------------------------------
__global__ __launch_bounds__(256) void cvtx_kernel(const float* __restrict__ x,
                                                   uint16_t* __restrict__ Xb) {
    size_t i = (size_t)blockIdx.x * 256 + threadIdx.x;  // 16384*256 float4s exact
    ((ushort4*)Xb)[i] = f4_to_bf4(((const float4*)x)[i]);
}
// convert ONE PAIR of experts' w1+w3 (experts p*2, p*2+1)
__global__ __launch_bounds__(256) void cvt13p_kernel(const float* __restrict__ w1,
                                                     const float* __restrict__ w3,
                                                     uint16_t* __restrict__ w1be,
                                                     uint16_t* __restrict__ w3be, int p) {
    size_t i = (size_t)blockIdx.x * 256 + threadIdx.x;  // 2*H*D/4 float4s exact
    size_t off = (size_t)p * 2 * H_DIM * D_DIM / 4;     // float4 offset of pair
    ((ushort4*)w1be)[i] = f4_to_bf4(((const float4*)w1)[off + i]);
    ((ushort4*)w3be)[i] = f4_to_bf4(((const float4*)w3)[off + i]);
}
// convert ONE PAIR of experts' w2
__global__ __launch_bounds__(256) void cvt2p_kernel(const float* __restrict__ w2,
                                                    uint16_t* __restrict__ w2b, int p) {
    size_t i = (size_t)blockIdx.x * 256 + threadIdx.x;  // 2*D*H/4 float4s exact
    size_t off = (size_t)p * 2 * D_DIM * H_DIM / 4;
    ((ushort4*)w2b)[i] = f4_to_bf4(((const float4*)w2)[off + i]);
}

// ---------------- gemm1 (pair of experts): hidden = silu(Xe@w1^T)*(Xe@w3^T) -
// 128(M) x 64(N, dual B1/B3), BK=32, single-buffer 16KB LDS.
// Grid EXACT: (43 n-tiles, 32 m-slots, 2 experts) — all blocks active in the
// balanced case (r9 lesson: padded grids dilute the dispatch window and halve
// occupancy). Data-dependent skew handled by the m_t += 32 stride loop.
// n-fastest order (r8 measured-best: 147us/pair, BW-fed at 2.26 TB/s).
// T2 swizzle kept (conflict-zero, r9): global src chunk ^= (row>>1)&3,
// linear gl_lds dest, read chunk ks = kq ^ ((rA>>1)&3).
__global__ __launch_bounds__(256) void gemm1_kernel(
    const uint16_t* __restrict__ Xb, const uint16_t* __restrict__ w1be,
    const uint16_t* __restrict__ w3be, const int* __restrict__ slot_tok,
    const int* __restrict__ cnts, const int* __restrict__ bases,
    uint16_t* __restrict__ hidden, int p) {
    int ez = blockIdx.z;                 // expert within pair
    int e = p * 2 + ez;
    int cnt = cnts[e];
    int n0 = blockIdx.x * 64;
    int base = bases[e];
    const uint16_t* w1p = w1be + (size_t)ez * H_DIM * D_DIM;
    const uint16_t* w3p = w3be + (size_t)ez * H_DIM * D_DIM;

    __shared__ __align__(16) uint16_t As[128 * 32];
    __shared__ __align__(16) uint16_t B1s[64 * 32];
    __shared__ __align__(16) uint16_t B3s[64 * 32];

    int tid = threadIdx.x;
    int w = tid >> 6, lane = tid & 63;
    int rA = lane & 15, kq = lane >> 4;
    int lr = lane >> 2, lc = lane & 3;  // staging: 16 rows x 4 chunks of 16B
    int slr = (lr >> 1) & 3;            // store-side chunk swizzle
    int ks = kq ^ ((rA >> 1) & 3);      // read-side chunk swizzle

    uint16_t* lA0 = &As[(w * 2 + 0) * 512];
    uint16_t* lA1 = &As[(w * 2 + 1) * 512];
    uint16_t* lB1 = &B1s[w * 512];
    uint16_t* lB3 = &B3s[w * 512];

    for (int m_t = blockIdx.y; m_t * 128 < cnt; m_t += 32) {  // usually 1 iter
        int m0 = m_t * 128;

        int tok0 = slot_tok[base + min(m0 + w * 32 + lr, cnt - 1)];
        int tok1 = slot_tok[base + min(m0 + w * 32 + 16 + lr, cnt - 1)];
        const uint16_t* pA0 = Xb + (size_t)tok0 * D_DIM + (lc ^ slr) * 8;
        const uint16_t* pA1 = Xb + (size_t)tok1 * D_DIM + (lc ^ slr) * 8;
        const uint16_t* pB1 = w1p + (size_t)(n0 + w * 16 + lr) * D_DIM + (lc ^ slr) * 8;
        const uint16_t* pB3 = w3p + (size_t)(n0 + w * 16 + lr) * D_DIM + (lc ^ slr) * 8;

        f32x4_t acc1[2][4], acc3[2][4];
#pragma unroll
        for (int r = 0; r < 2; ++r)
#pragma unroll
            for (int n = 0; n < 4; ++n) {
                acc1[r][n] = (f32x4_t){0.f, 0.f, 0.f, 0.f};
                acc3[r][n] = (f32x4_t){0.f, 0.f, 0.f, 0.f};
            }

        for (int k0 = 0; k0 < D_DIM; k0 += 32) {
            __syncthreads();
            gl_lds16(pA0, lA0);
            gl_lds16(pA1, lA1);
            gl_lds16(pB1, lB1);
            gl_lds16(pB3, lB3);
            pA0 += 32; pA1 += 32; pB1 += 32; pB3 += 32;
            __syncthreads();

            bf16x8_t a0 = *(const bf16x8_t*)&As[(w * 32 + rA) * 32 + ks * 8];
            bf16x8_t a1 = *(const bf16x8_t*)&As[(w * 32 + 16 + rA) * 32 + ks * 8];
#pragma unroll
            for (int n = 0; n < 4; ++n) {
                bf16x8_t b1 = *(const bf16x8_t*)&B1s[(n * 16 + rA) * 32 + ks * 8];
                bf16x8_t b3 = *(const bf16x8_t*)&B3s[(n * 16 + rA) * 32 + ks * 8];
                acc1[0][n] = __builtin_amdgcn_mfma_f32_16x16x32_bf16(a0, b1, acc1[0][n], 0, 0, 0);
                acc1[1][n] = __builtin_amdgcn_mfma_f32_16x16x32_bf16(a1, b1, acc1[1][n], 0, 0, 0);
                acc3[0][n] = __builtin_amdgcn_mfma_f32_16x16x32_bf16(a0, b3, acc3[0][n], 0, 0, 0);
                acc3[1][n] = __builtin_amdgcn_mfma_f32_16x16x32_bf16(a1, b3, acc3[1][n], 0, 0, 0);
            }
        }

#pragma unroll
        for (int r = 0; r < 2; ++r)
#pragma unroll
            for (int n = 0; n < 4; ++n)
#pragma unroll
                for (int i = 0; i < 4; ++i) {
                    int mrow = m0 + w * 32 + r * 16 + kq * 4 + i;
                    if (mrow < cnt) {
                        float gv = acc1[r][n][i];
                        float s = gv / (1.0f + __expf(-gv));
                        float h = s * acc3[r][n][i];
                        hidden[(size_t)(base + mrow) * H_DIM + n0 + n * 16 + rA] = f2bf(h);
                    }
                }
        __syncthreads();  // LDS reuse across m-iterations
    }
}

// ---------------- gemm2 (pair, FUSED): out[tok] += w_slot * (hidden @ w2^T) -
// atomicAdd(f32) into pre-zeroed out. Grid EXACT: (8 d-tiles, 32, 2) with
// stride-m loop; striped m%8 decode kept (r8 near-unique FETCH).
__global__ __launch_bounds__(256) void gemm2_kernel(
    const uint16_t* __restrict__ hidden, const uint16_t* __restrict__ w2b,
    const int* __restrict__ cnts, const int* __restrict__ bases,
    const int* __restrict__ slot_tok, const float* __restrict__ slot_w,
    float* __restrict__ out, int p) {
    int ez = blockIdx.z;
    int e = p * 2 + ez;
    int cnt = cnts[e];
    // lin in [0,256): j = lin>>3 in [0,32); m_t0 = (j>>3)*8 + lin&7 in [0,32)
    int lin = blockIdx.y * 8 + blockIdx.x;
    int c8 = lin & 7, j = lin >> 3;
    int m_t0 = (j >> 3) * 8 + c8;           // m_t % 8 == c8 (XCD stripe)
    int x_t = j & 7;
    int base = bases[e];
    int d0 = x_t * 128;

    __shared__ __align__(16) uint16_t As[128 * 32];
    __shared__ __align__(16) uint16_t Bs[128 * 32];

    int tid = threadIdx.x;
    int w = tid >> 6, lane = tid & 63;
    int rA = lane & 15, kq = lane >> 4;
    int lr = lane >> 2, lc = lane & 3;
    int mh = w & 1, nh = w >> 1;

    uint16_t* lA0 = &As[(w * 2 + 0) * 512];
    uint16_t* lA1 = &As[(w * 2 + 1) * 512];
    uint16_t* lB0 = &Bs[(w * 2 + 0) * 512];
    uint16_t* lB1 = &Bs[(w * 2 + 1) * 512];

    for (int m_t = m_t0; m_t * 128 < cnt; m_t += 32) {  // usually 1 iter
        int m0 = m_t * 128;

        int sl0 = base + min(m0 + w * 32 + lr, cnt - 1);
        int sl1 = base + min(m0 + w * 32 + 16 + lr, cnt - 1);
        const uint16_t* pA0 = hidden + (size_t)sl0 * H_DIM + lc * 8;
        const uint16_t* pA1 = hidden + (size_t)sl1 * H_DIM + lc * 8;
        const uint16_t* pB0 = w2b + (size_t)(ez * D_DIM + d0 + w * 32 + lr) * H_DIM + lc * 8;
        const uint16_t* pB1 = w2b + (size_t)(ez * D_DIM + d0 + w * 32 + 16 + lr) * H_DIM + lc * 8;

        f32x4_t acc[4][4];
#pragma unroll
        for (int mf = 0; mf < 4; ++mf)
#pragma unroll
            for (int nf = 0; nf < 4; ++nf) acc[mf][nf] = (f32x4_t){0.f, 0.f, 0.f, 0.f};

        for (int k0 = 0; k0 < H_DIM; k0 += 32) {  // 86 steps
            __syncthreads();
            gl_lds16(pA0, lA0);
            gl_lds16(pA1, lA1);
            gl_lds16(pB0, lB0);
            gl_lds16(pB1, lB1);
            pA0 += 32; pA1 += 32; pB0 += 32; pB1 += 32;
            __syncthreads();

            bf16x8_t a[4], b[4];
#pragma unroll
            for (int mf = 0; mf < 4; ++mf)
                a[mf] = *(const bf16x8_t*)&As[(mh * 64 + mf * 16 + rA) * 32 + kq * 8];
#pragma unroll
            for (int nf = 0; nf < 4; ++nf)
                b[nf] = *(const bf16x8_t*)&Bs[(nh * 64 + nf * 16 + rA) * 32 + kq * 8];
#pragma unroll
            for (int mf = 0; mf < 4; ++mf)
#pragma unroll
                for (int nf = 0; nf < 4; ++nf)
                    acc[mf][nf] = __builtin_amdgcn_mfma_f32_16x16x32_bf16(a[mf], b[nf], acc[mf][nf], 0, 0, 0);
        }

#pragma unroll
        for (int mf = 0; mf < 4; ++mf)
#pragma unroll
            for (int i = 0; i < 4; ++i) {
                int mr = m0 + mh * 64 + mf * 16 + kq * 4 + i;
                if (mr < cnt) {
                    int slot = base + mr;
                    float wgt = slot_w[slot];
                    int tok = slot_tok[slot];
                    float* yr = out + (size_t)tok * D_DIM + d0 + nh * 64;
#pragma unroll
                    for (int nf = 0; nf < 4; ++nf)
                        atomicAdd(&yr[nf * 16 + rA], wgt * acc[mf][nf][i]);
                }
            }
        __syncthreads();  // LDS reuse across m-iterations
    }
}

// ---------------- launch ----------------------------------------------------
extern "C" void kernel_launch(void* const* d_in, const int* in_sizes, int n_in,
                              void* d_out, int out_size, void* d_ws, size_t ws_size,
                              hipStream_t stream) {
    const float* x  = (const float*)d_in[0];
    const float* gw = (const float*)d_in[1];
    const float* w1 = (const float*)d_in[2];
    const float* w2 = (const float*)d_in[3];
    const float* w3 = (const float*)d_in[4];
    float* out = (float*)d_out;
    char* ws = (char*)d_ws;

    // meta (first 1 MiB) — counter arrays spread 256B apart.
    int*   counts_f = (int*)(ws + 0);
    int*   counts_s = (int*)(ws + 256);
    int*   fills_f  = (int*)(ws + 512);
    int*   fills_s  = (int*)(ws + 768);
    int*   bases    = (int*)(ws + 1024);
    int*   splits   = (int*)(ws + 1280);
    int*   cnts     = (int*)(ws + 1536);
    int*   topk_i   = (int*)(ws + 4096);
    float* topk_w   = (float*)(ws + 4096 + 1 * 131072);
    int*   slot_tok = (int*)(ws + 4096 + 2 * 131072);
    float* slot_w   = (float*)(ws + 4096 + 3 * 131072);

    // Workspace (total 237,502,464 B = 226.5 MiB < proven 245 MB):
    //   meta    @ 0       (1 MiB)
    //   hidden  @ 1 MiB   (32768*2752*2       = 180,355,072)
    //   Wpair   @ +hidden (2 experts w1 + w3  =  22,544,384)
    //     [w1be_pair 11.27MB][w3be_pair 11.27MB]
    //     w2b_pair (11.27MB) ALIASES w1be_pair — dead after gemm1p(p),
    //     rewritten by cvt2p(p) before gemm2p(p) (stream-serialized).
    //   Xb      @ +Wpair  (16384*1024*2       =  33,554,432)
    const size_t HID_OFF = 1ull << 20;
    const size_t W_OFF   = HID_OFF + (size_t)NSLOT * H_DIM * 2;
    const size_t WPAIR   = (size_t)2 * H_DIM * D_DIM * 2;      // 11,272,192 x2
    uint16_t* hidden = (uint16_t*)(ws + HID_OFF);
    uint16_t* w1be   = (uint16_t*)(ws + W_OFF);
    uint16_t* w3be   = (uint16_t*)(ws + W_OFF + WPAIR);
    uint16_t* w2b    = (uint16_t*)(ws + W_OFF);                // aliases w1be
    uint16_t* Xb     = (uint16_t*)(ws + W_OFF + 2 * WPAIR);

    hipMemsetAsync(ws, 0, 1024, stream);  // counts/fills
    // out accumulated via atomicAdd across all gemm2 pair-launches
    hipMemsetAsync(out, 0, (size_t)T_TOK * D_DIM * sizeof(float), stream);

    router_kernel<<<T_TOK / 4, 256, 0, stream>>>(x, gw, topk_i, topk_w);
    count_kernel<<<T_TOK / 256, 256, 0, stream>>>(topk_i, counts_f, counts_s);
    prefix_kernel<<<1, 1, 0, stream>>>(counts_f, counts_s, bases, splits, cnts);
    assign_kernel<<<T_TOK / 256, 256, 0, stream>>>(topk_i, topk_w, bases, splits,
                                                   fills_f, fills_s, slot_tok, slot_w);
    cvtx_kernel<<<T_TOK * D_DIM / 1024, 256, 0, stream>>>(x, Xb);

    // Producer->consumer pair pipeline + EXACT grids (stride-m loops inside).
    for (int p = 0; p < 4; ++p) {
        cvt13p_kernel<<<H_DIM * 2, 256, 0, stream>>>(w1, w3, w1be, w3be, p);
        gemm1_kernel<<<dim3(H_DIM / 64, 32, 2), 256, 0, stream>>>(
            Xb, w1be, w3be, slot_tok, cnts, bases, hidden, p);
        cvt2p_kernel<<<H_DIM * 2, 256, 0, stream>>>(w2, w2b, p);
        gemm2_kernel<<<dim3(8, 32, 2), 256, 0, stream>>>(
            hidden, w2b, cnts, bases, slot_tok, slot_w, out, p);
    }
}

// Round 11
// 1198.097 us; speedup vs baseline: 1.3678x; 1.3678x over previous
//
#include <hip/hip_runtime.h>
#include <hip/hip_bf16.h>
#include <stdint.h>

#define T_TOK 16384
#define D_DIM 1024
#define E_NUM 8
#define H_DIM 2752
#define NSLOT (T_TOK * 2)

typedef __bf16 bf16x8_t __attribute__((ext_vector_type(8)));
typedef float f32x4_t __attribute__((ext_vector_type(4)));

__device__ __forceinline__ uint16_t f2bf(float f) {
    union { float f; uint32_t u; } v; v.f = f;
    return (uint16_t)((v.u + 0x7FFFu + ((v.u >> 16) & 1u)) >> 16);  // RNE
}
__device__ __forceinline__ ushort4 f4_to_bf4(float4 v) {
    ushort4 r; r.x = f2bf(v.x); r.y = f2bf(v.y); r.z = f2bf(v.z); r.w = f2bf(v.w);
    return r;
}
// async global->LDS, 16B/lane; HW writes LDS at (wave-uniform base) + lane*16
__device__ __forceinline__ void gl_lds16(const uint16_t* g, uint16_t* l) {
    __builtin_amdgcn_global_load_lds((const __attribute__((address_space(1))) void*)g,
                                     (__attribute__((address_space(3))) void*)l,
                                     16, 0, 0);
}

// ---------------- router: fp64 logits, softmax top-2, NO atomics ------------
__global__ __launch_bounds__(256) void router_kernel(
    const float* __restrict__ x, const float* __restrict__ gw,
    int* __restrict__ topk_i, float* __restrict__ topk_w) {
    int tid = threadIdx.x;
    int t = blockIdx.x * 4 + (tid >> 6);
    int lane = tid & 63;
    const float* xr = x + (size_t)t * D_DIM;
    double acc[E_NUM];
#pragma unroll
    for (int e = 0; e < E_NUM; ++e) acc[e] = 0.0;
    for (int k = lane; k < D_DIM; k += 64) {
        double xv = (double)xr[k];
#pragma unroll
        for (int e = 0; e < E_NUM; ++e) acc[e] += xv * (double)gw[e * D_DIM + k];
    }
#pragma unroll
    for (int e = 0; e < E_NUM; ++e) {
        double v = acc[e];
        for (int off = 32; off > 0; off >>= 1) v += __shfl_down(v, off, 64);
        acc[e] = v;
    }
    if (lane == 0) {
        int i0 = 0; double m0 = acc[0];
#pragma unroll
        for (int e = 1; e < E_NUM; ++e) if (acc[e] > m0) { m0 = acc[e]; i0 = e; }
        int i1 = -1; double m1 = -1.0e300;
#pragma unroll
        for (int e = 0; e < E_NUM; ++e) if (e != i0 && acc[e] > m1) { m1 = acc[e]; i1 = e; }
        double e1 = exp(m1 - m0);
        double s = 1.0 + e1;
        topk_i[t * 2 + 0] = i0; topk_i[t * 2 + 1] = i1;
        topk_w[t * 2 + 0] = (float)(1.0 / s);
        topk_w[t * 2 + 1] = (float)(e1 / s);
    }
}

// ---------------- count: LDS-aggregated histogram (1024 global atomics) -----
__global__ __launch_bounds__(256) void count_kernel(
    const int* __restrict__ topk_i,
    int* __restrict__ counts_f, int* __restrict__ counts_s) {
    __shared__ int hf[E_NUM], hs[E_NUM];
    int tid = threadIdx.x;
    if (tid < E_NUM) { hf[tid] = 0; hs[tid] = 0; }
    __syncthreads();
    int t = blockIdx.x * 256 + tid;
    atomicAdd(&hf[topk_i[t * 2 + 0]], 1);
    atomicAdd(&hs[topk_i[t * 2 + 1]], 1);
    __syncthreads();
    if (tid < E_NUM) {
        if (hf[tid]) atomicAdd(&counts_f[tid], hf[tid]);
    } else if (tid < 2 * E_NUM) {
        int e = tid - E_NUM;
        if (hs[e]) atomicAdd(&counts_s[e], hs[e]);
    }
}

__global__ void prefix_kernel(const int* __restrict__ cf, const int* __restrict__ cs,
                              int* __restrict__ bases, int* __restrict__ splits,
                              int* __restrict__ cnts) {
    int s = 0;
    for (int e = 0; e < E_NUM; ++e) {
        bases[e] = s;
        splits[e] = s + cf[e];
        cnts[e] = cf[e] + cs[e];
        s += cnts[e];
    }
}

// ---------------- assign: block-aggregated ranks (1024 global atomics) ------
__global__ __launch_bounds__(256) void assign_kernel(
    const int* __restrict__ topk_i, const float* __restrict__ topk_w,
    const int* __restrict__ bases, const int* __restrict__ splits,
    int* __restrict__ fills_f, int* __restrict__ fills_s,
    int* __restrict__ slot_tok, float* __restrict__ slot_w) {
    __shared__ int hf[E_NUM], hs[E_NUM], bf[E_NUM], bs[E_NUM];
    int tid = threadIdx.x;
    if (tid < E_NUM) { hf[tid] = 0; hs[tid] = 0; }
    __syncthreads();
    int t = blockIdx.x * 256 + tid;
    int e0 = topk_i[t * 2 + 0], e1 = topk_i[t * 2 + 1];
    int r0 = atomicAdd(&hf[e0], 1);
    int r1 = atomicAdd(&hs[e1], 1);
    __syncthreads();
    if (tid < E_NUM) {
        bf[tid] = hf[tid] ? atomicAdd(&fills_f[tid], hf[tid]) : 0;
    } else if (tid < 2 * E_NUM) {
        int e = tid - E_NUM;
        bs[e] = hs[e] ? atomicAdd(&fills_s[e], hs[e]) : 0;
    }
    __syncthreads();
    int s0 = bases[e0] + bf[e0] + r0;
    int s1 = splits[e1] + bs[e1] + r1;
    slot_tok[s0] = t; slot_w[s0] = topk_w[t * 2 + 0];
    slot_tok[s1] = t; slot_w[s1] = topk_w[t * 2 + 1];
}

// ---------------- converts --------------------------------------------------
__global__ __launch_bounds__(256) void cvtx_kernel(const float* __restrict__ x,
                                                   uint16_t* __restrict__ Xb) {
    size_t i = (size_t)blockIdx.x * 256 + threadIdx.x;
    ((ushort4*)Xb)[i] = f4_to_bf4(((const float4*)x)[i]);
}
// convert 4 experts' w1+w3 in one launch (group g: experts g*4..g*4+3)
__global__ __launch_bounds__(256) void cvt13g_kernel(const float* __restrict__ w1,
                                                     const float* __restrict__ w3,
                                                     uint16_t* __restrict__ w1be,
                                                     uint16_t* __restrict__ w3be, int g) {
    size_t i = (size_t)blockIdx.x * 256 + threadIdx.x;
    size_t off = (size_t)g * 4 * H_DIM * D_DIM / 4;
    ((ushort4*)w1be)[i] = f4_to_bf4(((const float4*)w1)[off + i]);
    ((ushort4*)w3be)[i] = f4_to_bf4(((const float4*)w3)[off + i]);
}
__global__ __launch_bounds__(256) void cvt2_kernel(const float* __restrict__ w2,
                                                   uint16_t* __restrict__ w2b) {
    size_t i = (size_t)blockIdx.x * 256 + threadIdx.x;
    ((ushort4*)w2b)[i] = f4_to_bf4(((const float4*)w2)[i]);
}

// ============================================================================
// BK=64 GEMM inner loop: halves barrier events per K vs BK=32 (m233: the
// stage+drain+barrier event IS the 2-phase tax; depth/phases/maps nulled).
// LDS rows 128B -> 3-bit XOR chunk swizzle: phys_chunk = c ^ ((row>>1)&7).
// Store side via pre-swizzled GLOBAL source (per-thread constant
// src_chunk = (lane&7) ^ ((w*4 + lane>>4)&7), staged rows = 32i + 8w + r8);
// read side chunk = (kk*4+kq) ^ ((rA>>1)&7) (rowoff multiple of 16). 2-way
// bank spread = free (m136).
// ============================================================================

// ---------------- gemm1 (4 experts/launch): hidden = silu(Xe@w1^T)*(Xe@w3^T)
__global__ __launch_bounds__(256) void gemm1_kernel(
    const uint16_t* __restrict__ Xb, const uint16_t* __restrict__ w1be,
    const uint16_t* __restrict__ w3be, const int* __restrict__ slot_tok,
    const int* __restrict__ cnts, const int* __restrict__ bases,
    uint16_t* __restrict__ hidden, int g) {
    int ez = blockIdx.z;
    int e = g * 4 + ez;
    int cnt = cnts[e];
    int m0 = blockIdx.y * 128;
    if (m0 >= cnt) return;
    int n0 = blockIdx.x * 64;
    int base = bases[e];
    const uint16_t* w1p = w1be + (size_t)ez * H_DIM * D_DIM;
    const uint16_t* w3p = w3be + (size_t)ez * H_DIM * D_DIM;

    __shared__ __align__(16) uint16_t As[128 * 64];   // 16 KB
    __shared__ __align__(16) uint16_t B1s[64 * 64];   // 8 KB
    __shared__ __align__(16) uint16_t B3s[64 * 64];   // 8 KB

    int tid = threadIdx.x;
    int w = tid >> 6, lane = tid & 63;
    int rA = lane & 15, kq = lane >> 4;
    int r8 = lane >> 3;
    int srcc = (lane & 7) ^ ((w * 4 + (lane >> 4)) & 7);
    int xr = (rA >> 1) & 7;

    const uint16_t *pA0, *pA1, *pA2, *pA3, *pB1, *pB3;
    {
        int sr = w * 8 + r8;
        int t0 = slot_tok[base + min(m0 + 0 * 32 + sr, cnt - 1)];
        int t1 = slot_tok[base + min(m0 + 1 * 32 + sr, cnt - 1)];
        int t2 = slot_tok[base + min(m0 + 2 * 32 + sr, cnt - 1)];
        int t3 = slot_tok[base + min(m0 + 3 * 32 + sr, cnt - 1)];
        pA0 = Xb + (size_t)t0 * D_DIM + srcc * 8;
        pA1 = Xb + (size_t)t1 * D_DIM + srcc * 8;
        pA2 = Xb + (size_t)t2 * D_DIM + srcc * 8;
        pA3 = Xb + (size_t)t3 * D_DIM + srcc * 8;
        pB1 = w1p + (size_t)(n0 + sr) * D_DIM + srcc * 8;
        pB3 = w3p + (size_t)(n0 + sr) * D_DIM + srcc * 8;
    }
    uint16_t* lA = &As[(w * 8) * 64];
    uint16_t* lB1 = &B1s[(w * 8) * 64];
    uint16_t* lB3 = &B3s[(w * 8) * 64];

    f32x4_t acc1[2][4], acc3[2][4];
#pragma unroll
    for (int r = 0; r < 2; ++r)
#pragma unroll
        for (int n = 0; n < 4; ++n) {
            acc1[r][n] = (f32x4_t){0.f, 0.f, 0.f, 0.f};
            acc3[r][n] = (f32x4_t){0.f, 0.f, 0.f, 0.f};
        }

    for (int k0 = 0; k0 < D_DIM; k0 += 64) {  // 16 K-iters
        __syncthreads();
        gl_lds16(pA0, lA);
        gl_lds16(pA1, lA + 32 * 64);
        gl_lds16(pA2, lA + 64 * 64);
        gl_lds16(pA3, lA + 96 * 64);
        gl_lds16(pB1, lB1);
        gl_lds16(pB1 + 32 * D_DIM, lB1 + 32 * 64);
        gl_lds16(pB3, lB3);
        gl_lds16(pB3 + 32 * D_DIM, lB3 + 32 * 64);
        pA0 += 64; pA1 += 64; pA2 += 64; pA3 += 64; pB1 += 64; pB3 += 64;
        __syncthreads();

#pragma unroll
        for (int kk = 0; kk < 2; ++kk) {
            int ck = ((kk * 4 + kq) ^ xr) * 8;
            bf16x8_t a0 = *(const bf16x8_t*)&As[(w * 32 + rA) * 64 + ck];
            bf16x8_t a1 = *(const bf16x8_t*)&As[(w * 32 + 16 + rA) * 64 + ck];
#pragma unroll
            for (int n = 0; n < 4; ++n) {
                bf16x8_t b1 = *(const bf16x8_t*)&B1s[(n * 16 + rA) * 64 + ck];
                bf16x8_t b3 = *(const bf16x8_t*)&B3s[(n * 16 + rA) * 64 + ck];
                acc1[0][n] = __builtin_amdgcn_mfma_f32_16x16x32_bf16(a0, b1, acc1[0][n], 0, 0, 0);
                acc1[1][n] = __builtin_amdgcn_mfma_f32_16x16x32_bf16(a1, b1, acc1[1][n], 0, 0, 0);
                acc3[0][n] = __builtin_amdgcn_mfma_f32_16x16x32_bf16(a0, b3, acc3[0][n], 0, 0, 0);
                acc3[1][n] = __builtin_amdgcn_mfma_f32_16x16x32_bf16(a1, b3, acc3[1][n], 0, 0, 0);
            }
        }
    }

#pragma unroll
    for (int r = 0; r < 2; ++r)
#pragma unroll
        for (int n = 0; n < 4; ++n)
#pragma unroll
            for (int i = 0; i < 4; ++i) {
                int mrow = m0 + w * 32 + r * 16 + kq * 4 + i;
                if (mrow < cnt) {
                    float gv = acc1[r][n][i];
                    float s = gv / (1.0f + __expf(-gv));
                    float h = s * acc3[r][n][i];
                    hidden[(size_t)(base + mrow) * H_DIM + n0 + n * 16 + rA] = f2bf(h);
                }
            }
}

// ---------------- gemm2 (FUSED): out[tok] += w_slot * (hidden @ w2^T) -------
__global__ __launch_bounds__(256) void gemm2_kernel(
    const uint16_t* __restrict__ hidden, const uint16_t* __restrict__ w2b,
    const int* __restrict__ cnts, const int* __restrict__ bases,
    const int* __restrict__ slot_tok, const float* __restrict__ slot_w,
    float* __restrict__ out) {
    int e = blockIdx.z;
    int cnt = cnts[e];
    int lin = blockIdx.y * 8 + blockIdx.x;
    int c8 = lin & 7, j = lin >> 3;
    int m_t = (j >> 3) * 8 + c8;             // m_t % 8 == c8 (prefix-safe stripe)
    int x_t = j & 7;
    int m0 = m_t * 128;
    if (m0 >= cnt) return;
    int base = bases[e];
    int d0 = x_t * 128;

    __shared__ __align__(16) uint16_t As[128 * 64];  // 16 KB
    __shared__ __align__(16) uint16_t Bs[128 * 64];  // 16 KB

    int tid = threadIdx.x;
    int w = tid >> 6, lane = tid & 63;
    int rA = lane & 15, kq = lane >> 4;
    int r8 = lane >> 3;
    int srcc = (lane & 7) ^ ((w * 4 + (lane >> 4)) & 7);
    int xr = (rA >> 1) & 7;
    int mh = w & 1, nh = w >> 1;

    const uint16_t *pA0, *pA1, *pA2, *pA3, *pB;
    {
        int sr = w * 8 + r8;
        int s0 = base + min(m0 + 0 * 32 + sr, cnt - 1);
        int s1 = base + min(m0 + 1 * 32 + sr, cnt - 1);
        int s2 = base + min(m0 + 2 * 32 + sr, cnt - 1);
        int s3 = base + min(m0 + 3 * 32 + sr, cnt - 1);
        pA0 = hidden + (size_t)s0 * H_DIM + srcc * 8;
        pA1 = hidden + (size_t)s1 * H_DIM + srcc * 8;
        pA2 = hidden + (size_t)s2 * H_DIM + srcc * 8;
        pA3 = hidden + (size_t)s3 * H_DIM + srcc * 8;
        pB = w2b + (size_t)(e * D_DIM + d0 + sr) * H_DIM + srcc * 8;
    }
    uint16_t* lA = &As[(w * 8) * 64];
    uint16_t* lB = &Bs[(w * 8) * 64];

    f32x4_t acc[4][4];
#pragma unroll
    for (int mf = 0; mf < 4; ++mf)
#pragma unroll
        for (int nf = 0; nf < 4; ++nf) acc[mf][nf] = (f32x4_t){0.f, 0.f, 0.f, 0.f};

    for (int k0 = 0; k0 < H_DIM; k0 += 64) {  // 43 K-iters
        __syncthreads();
        gl_lds16(pA0, lA);
        gl_lds16(pA1, lA + 32 * 64);
        gl_lds16(pA2, lA + 64 * 64);
        gl_lds16(pA3, lA + 96 * 64);
        gl_lds16(pB, lB);
        gl_lds16(pB + 32 * H_DIM, lB + 32 * 64);
        gl_lds16(pB + 64 * H_DIM, lB + 64 * 64);
        gl_lds16(pB + 96 * H_DIM, lB + 96 * 64);
        pA0 += 64; pA1 += 64; pA2 += 64; pA3 += 64; pB += 64;
        __syncthreads();

#pragma unroll
        for (int kk = 0; kk < 2; ++kk) {
            int ck = ((kk * 4 + kq) ^ xr) * 8;
            bf16x8_t a[4], b[4];
#pragma unroll
            for (int mf = 0; mf < 4; ++mf)
                a[mf] = *(const bf16x8_t*)&As[(mh * 64 + mf * 16 + rA) * 64 + ck];
#pragma unroll
            for (int nf = 0; nf < 4; ++nf)
                b[nf] = *(const bf16x8_t*)&Bs[(nh * 64 + nf * 16 + rA) * 64 + ck];
#pragma unroll
            for (int mf = 0; mf < 4; ++mf)
#pragma unroll
                for (int nf = 0; nf < 4; ++nf)
                    acc[mf][nf] = __builtin_amdgcn_mfma_f32_16x16x32_bf16(a[mf], b[nf], acc[mf][nf], 0, 0, 0);
        }
    }

#pragma unroll
    for (int mf = 0; mf < 4; ++mf)
#pragma unroll
        for (int i = 0; i < 4; ++i) {
            int mr = m0 + mh * 64 + mf * 16 + kq * 4 + i;
            if (mr < cnt) {
                int slot = base + mr;
                float wgt = slot_w[slot];
                int tok = slot_tok[slot];
                float* yr = out + (size_t)tok * D_DIM + d0 + nh * 64;
#pragma unroll
                for (int nf = 0; nf < 4; ++nf)
                    atomicAdd(&yr[nf * 16 + rA], wgt * acc[mf][nf][i]);
            }
        }
}

// ---------------- launch ----------------------------------------------------
extern "C" void kernel_launch(void* const* d_in, const int* in_sizes, int n_in,
                              void* d_out, int out_size, void* d_ws, size_t ws_size,
                              hipStream_t stream) {
    const float* x  = (const float*)d_in[0];
    const float* gw = (const float*)d_in[1];
    const float* w1 = (const float*)d_in[2];
    const float* w2 = (const float*)d_in[3];
    const float* w3 = (const float*)d_in[4];
    float* out = (float*)d_out;
    char* ws = (char*)d_ws;

    int*   counts_f = (int*)(ws + 0);
    int*   counts_s = (int*)(ws + 256);
    int*   fills_f  = (int*)(ws + 512);
    int*   fills_s  = (int*)(ws + 768);
    int*   bases    = (int*)(ws + 1024);
    int*   splits   = (int*)(ws + 1280);
    int*   cnts     = (int*)(ws + 1536);
    int*   topk_i   = (int*)(ws + 4096);
    float* topk_w   = (float*)(ws + 4096 + 1 * 131072);
    int*   slot_tok = (int*)(ws + 4096 + 2 * 131072);
    float* slot_w   = (float*)(ws + 4096 + 3 * 131072);

    // r5 layout: hidden @4MiB (180.36MB); W region 45.09MB after hidden
    // (gemm1: w1be+w3be group; gemm2: w2b). Xb in d_out (dead until gemm2).
    const size_t HID_OFF = 4ull << 20;
    const size_t W_OFF   = HID_OFF + (size_t)NSLOT * H_DIM * 2;
    const size_t W1SZ    = (size_t)H_DIM * D_DIM * 2;
    uint16_t* hidden = (uint16_t*)(ws + HID_OFF);
    uint16_t* w1be   = (uint16_t*)(ws + W_OFF);
    uint16_t* w3be   = (uint16_t*)(ws + W_OFF + 4 * W1SZ);
    uint16_t* w2b    = (uint16_t*)(ws + W_OFF);
    uint16_t* Xb     = (uint16_t*)d_out;

    hipMemsetAsync(ws, 0, 1024, stream);

    router_kernel<<<T_TOK / 4, 256, 0, stream>>>(x, gw, topk_i, topk_w);
    count_kernel<<<T_TOK / 256, 256, 0, stream>>>(topk_i, counts_f, counts_s);
    prefix_kernel<<<1, 1, 0, stream>>>(counts_f, counts_s, bases, splits, cnts);
    assign_kernel<<<T_TOK / 256, 256, 0, stream>>>(topk_i, topk_w, bases, splits,
                                                   fills_f, fills_s, slot_tok, slot_w);
    cvtx_kernel<<<T_TOK * D_DIM / 1024, 256, 0, stream>>>(x, Xb);

    for (int g = 0; g < 2; ++g) {
        cvt13g_kernel<<<H_DIM * 4, 256, 0, stream>>>(w1, w3, w1be, w3be, g);
        gemm1_kernel<<<dim3(H_DIM / 64, 128, 4), 256, 0, stream>>>(
            Xb, w1be, w3be, slot_tok, cnts, bases, hidden, g);
    }

    hipMemsetAsync(out, 0, (size_t)T_TOK * D_DIM * sizeof(float), stream);
    cvt2_kernel<<<E_NUM * D_DIM * H_DIM / 1024, 256, 0, stream>>>(w2, w2b);
    gemm2_kernel<<<dim3(8, 128, E_NUM), 256, 0, stream>>>(
        hidden, w2b, cnts, bases, slot_tok, slot_w, out);
}